// Round 7
// baseline (37.855 us; speedup 1.0000x reference)
//
#include <hip/hip_runtime.h>
#include <cmath>

#define LLEN 131072
#define IIRL 16384
#define CHUNK 8192            // window (16384) spans exactly 2 prev chunks
#define NBLK (LLEN / CHUNK)   // 16 chunks per row
#define TPB 512
#define EPT (CHUNK / TPB)     // 16 elements per thread
#define NW (TPB / 64)         // 8 waves

__device__ __forceinline__ float powiu(float b, unsigned e) {
    float r = 1.0f;
    while (e) { if (e & 1u) r *= b; b *= b; e >>= 1; }
    return r;
}

__device__ __forceinline__ float sigmoidf(float z) {
    return 1.0f / (1.0f + __expf(-z));
}

// ---------------------------------------------------------------------------
// Independent blocks (no cross-block sync). CHUNK=8192, IIR window 16384 =>
// chunk c depends only on {c, c-1, c-2}:
//   carry = env[start-1] = T1(c-1) + alpha^8192 * T2(c-2)
// T(k) = zero-init weighted total of chunk k (reduction only).
// Phase A: 3 serial chains consume loads directly (tiny register state).
// Phase B: re-read own tile (cache-hot), recompute b, env e-chain, fast
// hardware transcendentals for the quadratic-knee gain, write both channels.
// env[t] = a*env[t-1] + (1-a)*(ls[t] - a^16384*ls[t-16384]), ls = mean_c(x^2)
// ---------------------------------------------------------------------------
__global__ __launch_bounds__(TPB, 6) void k_fused(
    const float* __restrict__ x, const float* __restrict__ za,
    const float* __restrict__ lt, const float* __restrict__ lr,
    const float* __restrict__ lk, float* __restrict__ out)
{
    // XCD-aware bijective swizzle: consecutive chunks of a row -> same XCD.
    const int d     = blockIdx.y * gridDim.x + blockIdx.x;
    const int total = gridDim.x * gridDim.y;       // 16*N, % 8 == 0
    const int per   = total >> 3;
    const int w     = (d & 7) * per + (d >> 3);
    const int chunk = w % NBLK, n = w / NBLK;

    const int tid = threadIdx.x, lane = tid & 63, wid = tid >> 6;

    const float alpha = sigmoidf(za[n]);
    const float omah  = 0.5f * (1.0f - alpha);
    const float A16K  = powiu(alpha, IIRL);   // 0 unless alpha > 0.9947
    const float Tthr  = lt[n] - 6.0f;
    const float ratio = 1.0f + __expf(lr[n]);
    const float knee  = __expf(lk[n] - 1.0f);
    const float coef  = (1.0f / ratio - 1.0f) / knee;

    const long  base = (long)n * 2 * LLEN + (long)chunk * CHUNK;
    const float* x0 = x + base;
    const float* x1 = x0 + LLEN;
    const int j0 = tid * EPT;

    const float a16   = powiu(alpha, 16u);    // per-thread segment weight
    const float A1024 = powiu(a16, 64u);      // per-wave segment weight

    // ---- phase A: three serial chains, loads consumed directly ----
    float s = 0.0f, s1 = 0.0f, s2 = 0.0f;
    {
        const float4* p0 = reinterpret_cast<const float4*>(x0 + j0);
        const float4* p1 = reinterpret_cast<const float4*>(x1 + j0);
        const float4* q0 = reinterpret_cast<const float4*>(x0 - 2*CHUNK + j0);
        const float4* q1 = reinterpret_cast<const float4*>(x1 - 2*CHUNK + j0);
        #pragma unroll
        for (int q = 0; q < 4; ++q) {
            float4 a = p0[q], c = p1[q];
            float b0 = omah * fmaf(a.x, a.x, c.x*c.x);
            float b1 = omah * fmaf(a.y, a.y, c.y*c.y);
            float b2 = omah * fmaf(a.z, a.z, c.z*c.z);
            float b3 = omah * fmaf(a.w, a.w, c.w*c.w);
            if (A16K != 0.0f && chunk > 1) {     // rare exact-tail path
                float4 ta = q0[q], tc = q1[q];
                const float sc = A16K * omah;
                b0 -= sc * fmaf(ta.x, ta.x, tc.x*tc.x);
                b1 -= sc * fmaf(ta.y, ta.y, tc.y*tc.y);
                b2 -= sc * fmaf(ta.z, ta.z, tc.z*tc.z);
                b3 -= sc * fmaf(ta.w, ta.w, tc.w*tc.w);
            }
            s = fmaf(alpha, s, b0); s = fmaf(alpha, s, b1);
            s = fmaf(alpha, s, b2); s = fmaf(alpha, s, b3);
        }
    }
    if (chunk > 0) {
        const float4* p0 = reinterpret_cast<const float4*>(x0 - CHUNK + j0);
        const float4* p1 = reinterpret_cast<const float4*>(x1 - CHUNK + j0);
        #pragma unroll
        for (int q = 0; q < 4; ++q) {
            float4 a = p0[q], c = p1[q];
            s1 = fmaf(alpha, s1, omah * fmaf(a.x, a.x, c.x*c.x));
            s1 = fmaf(alpha, s1, omah * fmaf(a.y, a.y, c.y*c.y));
            s1 = fmaf(alpha, s1, omah * fmaf(a.z, a.z, c.z*c.z));
            s1 = fmaf(alpha, s1, omah * fmaf(a.w, a.w, c.w*c.w));
        }
    }
    if (chunk > 1) {
        const float4* p0 = reinterpret_cast<const float4*>(x0 - 2*CHUNK + j0);
        const float4* p1 = reinterpret_cast<const float4*>(x1 - 2*CHUNK + j0);
        #pragma unroll
        for (int q = 0; q < 4; ++q) {
            float4 a = p0[q], c = p1[q];
            s2 = fmaf(alpha, s2, omah * fmaf(a.x, a.x, c.x*c.x));
            s2 = fmaf(alpha, s2, omah * fmaf(a.y, a.y, c.y*c.y));
            s2 = fmaf(alpha, s2, omah * fmaf(a.z, a.z, c.z*c.z));
            s2 = fmaf(alpha, s2, omah * fmaf(a.w, a.w, c.w*c.w));
        }
    }

    // ---- wave inclusive scan (own) ----
    float v = s, g = a16;
    #pragma unroll
    for (int off = 1; off < 64; off <<= 1) {
        float y = __shfl_up(v, off, 64);
        if (lane >= off) v = fmaf(g, y, v);
        g *= g;
    }
    float Ew = __shfl_up(v, 1, 64);
    if (lane == 0) Ew = 0.0f;

    // wave weighted totals (prev1, prev2): scale by a16^(63-lane), butterfly
    const float wscale = powiu(a16, (unsigned)(63 - lane));
    float t1 = s1 * wscale, t2 = s2 * wscale;
    #pragma unroll
    for (int off = 32; off; off >>= 1) {
        t1 += __shfl_xor(t1, off, 64);
        t2 += __shfl_xor(t2, off, 64);
    }

    __shared__ float wtB[NW], wtP1[NW], wtP2[NW];
    if (lane == 63) { wtB[wid] = v; wtP1[wid] = t1; wtP2[wid] = t2; }
    __syncthreads();

    float T1 = 0.0f, T2 = 0.0f;
    #pragma unroll
    for (int ww = 0; ww < NW; ++ww) {
        T1 = fmaf(A1024, T1, wtP1[ww]);
        T2 = fmaf(A1024, T2, wtP2[ww]);
    }
    const float A8192 = powiu(A1024, 8u);
    const float carry = fmaf(A8192, T2, T1);

    float wc = 0.0f;
    for (int ww = 0; ww < wid; ++ww) wc = fmaf(A1024, wc, wtB[ww]);

    const float a16l = powiu(a16, (unsigned)lane);
    float pre_blk = fmaf(a16l, wc, Ew);
    float e = fmaf(a16l * powiu(A1024, (unsigned)wid), carry, pre_blk);

    // ---- phase B: re-read own tile (cache-hot), env + gain + write ----
    {
        const float4* p0 = reinterpret_cast<const float4*>(x0 + j0);
        const float4* p1 = reinterpret_cast<const float4*>(x1 + j0);
        const float4* q0 = reinterpret_cast<const float4*>(x0 - 2*CHUNK + j0);
        const float4* q1 = reinterpret_cast<const float4*>(x1 - 2*CHUNK + j0);
        #pragma unroll
        for (int q = 0; q < 4; ++q) {
            float4 a = p0[q], c = p1[q];
            float4 tcor = make_float4(0.f, 0.f, 0.f, 0.f);
            if (A16K != 0.0f && chunk > 1) {     // rare exact-tail path
                float4 ta = q0[q], tc = q1[q];
                const float sc = A16K * omah;
                tcor.x = sc * fmaf(ta.x, ta.x, tc.x*tc.x);
                tcor.y = sc * fmaf(ta.y, ta.y, tc.y*tc.y);
                tcor.z = sc * fmaf(ta.z, ta.z, tc.z*tc.z);
                tcor.w = sc * fmaf(ta.w, ta.w, tc.w*tc.w);
            }
            float4 oa, ob;
            const float* ia = reinterpret_cast<const float*>(&a);
            const float* ib = reinterpret_cast<const float*>(&c);
            const float* it = reinterpret_cast<const float*>(&tcor);
            float* poa = reinterpret_cast<float*>(&oa);
            float* pob = reinterpret_cast<float*>(&ob);
            #pragma unroll
            for (int k = 0; k < 4; ++k) {
                float bi = omah * fmaf(ia[k], ia[k], ib[k]*ib[k]) - it[k];
                e = fmaf(alpha, e, bi);
                float le = __logf(e + 1e-5f);
                float xk = knee * (le - Tthr);
                float sp = fmaxf(xk, 0.0f) + __logf(1.0f + __expf(-fabsf(xk)));
                float gain = __expf(coef * sp);
                poa[k] = gain * ia[k];
                pob[k] = gain * ib[k];
            }
            reinterpret_cast<float4*>(out + base + j0)[q]        = oa;
            reinterpret_cast<float4*>(out + base + LLEN + j0)[q] = ob;
        }
    }
}

extern "C" void kernel_launch(void* const* d_in, const int* in_sizes, int n_in,
                              void* d_out, int out_size, void* d_ws, size_t ws_size,
                              hipStream_t stream) {
    const float* x  = (const float*)d_in[0];
    const float* za = (const float*)d_in[1];
    const float* lt = (const float*)d_in[2];
    const float* lr = (const float*)d_in[3];
    const float* lk = (const float*)d_in[4];
    float* out = (float*)d_out;

    const int N = in_sizes[1];             // z_alpha is (N,1)
    dim3 grid(NBLK, N), block(TPB);
    k_fused<<<grid, block, 0, stream>>>(x, za, lt, lr, lk, out);
}

// Round 8
// 21.963 us; speedup vs baseline: 1.7236x; 1.7236x over previous
//
#include <hip/hip_runtime.h>
#include <cmath>

#define LLEN 131072
#define IIRL 16384
#define CHUNK 8192            // IIR window (16384) = exactly 2 prev chunks
#define NBLK (LLEN / CHUNK)   // 16 chunks per row
#define TPB 512
#define NW (TPB / 64)         // 8 waves; 1024 elements per wave segment
// layout within a wave segment: elem i = 4*(64*q + lane) + m, q,m in [0,4)
// -> every float4 load/store is lane-contiguous (64 lanes x 16B = 1KiB)

__device__ __forceinline__ float powiu(float b, unsigned e) {
    float r = 1.0f;
    while (e) { if (e & 1u) r *= b; b *= b; e >>= 1; }
    return r;
}

__device__ __forceinline__ float sigmoidf(float z) {
    return 1.0f / (1.0f + __expf(-z));
}

// ---------------------------------------------------------------------------
// Independent blocks (no cross-block sync). Chunk c depends on {c, c-1, c-2}:
//   carry = env[start-1] = T(c-1) + alpha^8192 * T(c-2)
// T(k) = zero-init weighted total of chunk k (butterfly reduction only).
// Own chunk: 4 runs/thread -> 4 interleaved wave scans (ratio alpha^4),
// run-block carries via alpha^256, waves combined via alpha^1024 in LDS.
// env[t] = a*env[t-1] + (1-a)*(ls[t] - a^16384*ls[t-16384]), ls = mean_c(x^2)
// ---------------------------------------------------------------------------
__global__ __launch_bounds__(TPB, 4) void k_fused(
    const float* __restrict__ x, const float* __restrict__ za,
    const float* __restrict__ lt, const float* __restrict__ lr,
    const float* __restrict__ lk, float* __restrict__ out)
{
    // XCD-aware bijective swizzle: consecutive chunks of a row -> same XCD.
    const int d     = blockIdx.y * gridDim.x + blockIdx.x;
    const int per   = (gridDim.x * gridDim.y) >> 3;   // total % 8 == 0
    const int w     = (d & 7) * per + (d >> 3);
    const int chunk = w % NBLK, n = w / NBLK;

    const int tid = threadIdx.x, lane = tid & 63, wid = tid >> 6;

    const float alpha = sigmoidf(za[n]);
    const float omah  = 0.5f * (1.0f - alpha);
    const float A16K  = powiu(alpha, IIRL);   // 0 unless alpha > 0.9947
    const float Tthr  = lt[n] - 6.0f;
    const float ratio = 1.0f + __expf(lr[n]);
    const float knee  = __expf(lk[n] - 1.0f);
    const float coef  = (1.0f / ratio - 1.0f) / knee;

    const float a4    = (alpha * alpha) * (alpha * alpha);
    const float a256  = powiu(a4, 64u);
    const float A1024 = powiu(a256, 4u);
    const float A8192 = powiu(A1024, 8u);

    const long  base = (long)n * 2 * LLEN + (long)chunk * CHUNK;
    const float* x0 = x + base;
    const float* x1 = x0 + LLEN;
    const int woff = wid * 1024;          // wave segment offset in chunk

    // ---- own tile: coalesced loads, kept in registers ----
    float4 xa[4], xb[4];
    {
        const float4* p0 = reinterpret_cast<const float4*>(x0 + woff);
        const float4* p1 = reinterpret_cast<const float4*>(x1 + woff);
        #pragma unroll
        for (int q = 0; q < 4; ++q) {
            xa[q] = p0[q * 64 + lane];
            xb[q] = p1[q * 64 + lane];
        }
    }

    // b values for own tile (recurrence input), incl. rare exact-tail term
    float b[4][4];
    #pragma unroll
    for (int q = 0; q < 4; ++q) {
        float4 a = xa[q], c = xb[q];
        b[q][0] = omah * fmaf(a.x, a.x, c.x * c.x);
        b[q][1] = omah * fmaf(a.y, a.y, c.y * c.y);
        b[q][2] = omah * fmaf(a.z, a.z, c.z * c.z);
        b[q][3] = omah * fmaf(a.w, a.w, c.w * c.w);
    }
    if (A16K != 0.0f && chunk > 1) {      // uniform per-row branch, ~never
        const float4* q0 = reinterpret_cast<const float4*>(x0 - 2*CHUNK + woff);
        const float4* q1 = reinterpret_cast<const float4*>(x1 - 2*CHUNK + woff);
        const float sc = A16K * omah;
        #pragma unroll
        for (int q = 0; q < 4; ++q) {
            float4 a = q0[q * 64 + lane], c = q1[q * 64 + lane];
            b[q][0] -= sc * fmaf(a.x, a.x, c.x * c.x);
            b[q][1] -= sc * fmaf(a.y, a.y, c.y * c.y);
            b[q][2] -= sc * fmaf(a.z, a.z, c.z * c.z);
            b[q][3] -= sc * fmaf(a.w, a.w, c.w * c.w);
        }
    }

    // per-thread run totals rt_q = a^3 b0 + a^2 b1 + a b2 + b3 (4 indep chains)
    float rt[4];
    #pragma unroll
    for (int q = 0; q < 4; ++q) {
        float s = b[q][0];
        s = fmaf(alpha, s, b[q][1]);
        s = fmaf(alpha, s, b[q][2]);
        s = fmaf(alpha, s, b[q][3]);
        rt[q] = s;
    }

    // ---- prev-chunk carry contributions (reduction only) ----
    float u = 0.0f;   // per-thread combined contribution to T1 + A8192*T2
    if (chunk > 0) {
        const float4* r0 = reinterpret_cast<const float4*>(x0 - CHUNK + woff);
        const float4* r1 = reinterpret_cast<const float4*>(x1 - CHUNK + woff);
        float u1 = 0.0f;
        #pragma unroll
        for (int q = 0; q < 4; ++q) {
            float4 a = r0[q * 64 + lane], c = r1[q * 64 + lane];
            float s = omah * fmaf(a.x, a.x, c.x * c.x);
            s = fmaf(alpha, s, omah * fmaf(a.y, a.y, c.y * c.y));
            s = fmaf(alpha, s, omah * fmaf(a.z, a.z, c.z * c.z));
            s = fmaf(alpha, s, omah * fmaf(a.w, a.w, c.w * c.w));
            u1 = fmaf(a256, u1, s);           // Horner over run blocks
        }
        u = u1;
    }
    if (chunk > 1) {
        const float4* r0 = reinterpret_cast<const float4*>(x0 - 2*CHUNK + woff);
        const float4* r1 = reinterpret_cast<const float4*>(x1 - 2*CHUNK + woff);
        float u2 = 0.0f;
        #pragma unroll
        for (int q = 0; q < 4; ++q) {
            float4 a = r0[q * 64 + lane], c = r1[q * 64 + lane];
            float s = omah * fmaf(a.x, a.x, c.x * c.x);
            s = fmaf(alpha, s, omah * fmaf(a.y, a.y, c.y * c.y));
            s = fmaf(alpha, s, omah * fmaf(a.z, a.z, c.z * c.z));
            s = fmaf(alpha, s, omah * fmaf(a.w, a.w, c.w * c.w));
            u2 = fmaf(a256, u2, s);
        }
        u = fmaf(A8192, u2, u);
    }
    u *= powiu(a4, (unsigned)(63 - lane));    // lane weight within wave
    #pragma unroll
    for (int off = 32; off; off >>= 1) u += __shfl_xor(u, off, 64);

    // ---- 4 interleaved wave scans over lanes (ratio a^4) ----
    float v0 = rt[0], v1 = rt[1], v2 = rt[2], v3 = rt[3];
    float g = a4;
    #pragma unroll
    for (int off = 1; off < 64; off <<= 1) {
        float y0 = __shfl_up(v0, off, 64);
        float y1 = __shfl_up(v1, off, 64);
        float y2 = __shfl_up(v2, off, 64);
        float y3 = __shfl_up(v3, off, 64);
        if (lane >= off) {
            v0 = fmaf(g, y0, v0); v1 = fmaf(g, y1, v1);
            v2 = fmaf(g, y2, v2); v3 = fmaf(g, y3, v3);
        }
        g *= g;
    }
    float Ex[4];
    Ex[0] = __shfl_up(v0, 1, 64); Ex[1] = __shfl_up(v1, 1, 64);
    Ex[2] = __shfl_up(v2, 1, 64); Ex[3] = __shfl_up(v3, 1, 64);
    if (lane == 0) { Ex[0] = Ex[1] = Ex[2] = Ex[3] = 0.0f; }
    float S[4];
    S[0] = __shfl(v0, 63, 64); S[1] = __shfl(v1, 63, 64);
    S[2] = __shfl(v2, 63, 64); S[3] = __shfl(v3, 63, 64);

    // wave total (1024 elems): Horner over run blocks
    float W = S[0];
    W = fmaf(a256, W, S[1]); W = fmaf(a256, W, S[2]); W = fmaf(a256, W, S[3]);

    __shared__ float wtB[NW], wtP[NW];
    if (lane == 0) { wtB[wid] = W; wtP[wid] = u; }
    __syncthreads();

    // block-level: carry from prev chunks + exclusive prefix over waves
    float C = 0.0f;
    #pragma unroll
    for (int ww = 0; ww < NW; ++ww) C = fmaf(A1024, C, wtP[ww]);
    float wc = 0.0f;
    for (int ww = 0; ww < wid; ++ww) wc = fmaf(A1024, wc, wtB[ww]);

    const float e_wave = fmaf(powiu(A1024, (unsigned)wid), C, wc);
    const float a4l    = powiu(a4, (unsigned)lane);

    // ---- apply gain + coalesced writes ----
    float cq = e_wave;                    // env before run-block q
    float4* o0 = reinterpret_cast<float4*>(out + base + woff);
    float4* o1 = reinterpret_cast<float4*>(out + base + LLEN + woff);
    #pragma unroll
    for (int q = 0; q < 4; ++q) {
        float e = fmaf(a4l, cq, Ex[q]);   // env before this thread's run
        cq = fmaf(a256, cq, S[q]);        // advance to next run block
        float4 a = xa[q], c = xb[q];
        float4 oa, ob;
        const float* ia = reinterpret_cast<const float*>(&a);
        const float* ib = reinterpret_cast<const float*>(&c);
        float* poa = reinterpret_cast<float*>(&oa);
        float* pob = reinterpret_cast<float*>(&ob);
        #pragma unroll
        for (int m = 0; m < 4; ++m) {
            e = fmaf(alpha, e, b[q][m]);
            float le = __logf(e + 1e-5f);
            float xk = knee * (le - Tthr);
            float sp = fmaxf(xk, 0.0f) + __logf(1.0f + __expf(-fabsf(xk)));
            float gain = __expf(coef * sp);
            poa[m] = gain * ia[m];
            pob[m] = gain * ib[m];
        }
        o0[q * 64 + lane] = oa;
        o1[q * 64 + lane] = ob;
    }
}

extern "C" void kernel_launch(void* const* d_in, const int* in_sizes, int n_in,
                              void* d_out, int out_size, void* d_ws, size_t ws_size,
                              hipStream_t stream) {
    const float* x  = (const float*)d_in[0];
    const float* za = (const float*)d_in[1];
    const float* lt = (const float*)d_in[2];
    const float* lr = (const float*)d_in[3];
    const float* lk = (const float*)d_in[4];
    float* out = (float*)d_out;

    const int N = in_sizes[1];             // z_alpha is (N,1)
    dim3 grid(NBLK, N), block(TPB);
    k_fused<<<grid, block, 0, stream>>>(x, za, lt, lr, lk, out);
}

// Round 9
// 21.938 us; speedup vs baseline: 1.7255x; 1.0011x over previous
//
#include <hip/hip_runtime.h>
#include <cmath>

#define LLEN 131072
#define IIRL 16384
#define CHUNK 16384           // == IIRL: window = exactly 1 prev chunk
#define NBLK (LLEN / CHUNK)   // 8 chunks per row
#define TPB 1024
#define NW (TPB / 64)         // 16 waves; 1024 elements per wave segment
// layout within a wave segment: elem i = 4*(64*q + lane) + m, q,m in [0,4)
// -> every float4 load/store is lane-contiguous (64 lanes x 16B = 1KiB)

__device__ __forceinline__ float powiu(float b, unsigned e) {
    float r = 1.0f;
    while (e) { if (e & 1u) r *= b; b *= b; e >>= 1; }
    return r;
}

__device__ __forceinline__ float sigmoidf(float z) {
    return 1.0f / (1.0f + __expf(-z));
}

// ---------------------------------------------------------------------------
// Independent blocks (no cross-block sync). CHUNK == IIRL => chunk c depends
// only on {c, c-1}: carry = env[start-1] = T(c-1) = zero-init weighted total
// of the prev chunk (exactly the FIR window). The truncation tail
// ls[t-16384] also lives in c-1 at the same offset (shared read).
// Own chunk: 4 runs/thread -> 4 interleaved wave scans (ratio alpha^4),
// run-block carries via alpha^256, waves combined via alpha^1024 in LDS.
// env[t] = a*env[t-1] + (1-a)*(ls[t] - a^16384*ls[t-16384]), ls = mean_c(x^2)
// ---------------------------------------------------------------------------
__global__ __launch_bounds__(TPB) void k_fused(
    const float* __restrict__ x, const float* __restrict__ za,
    const float* __restrict__ lt, const float* __restrict__ lr,
    const float* __restrict__ lk, float* __restrict__ out)
{
    // XCD-aware bijective swizzle: consecutive chunks of a row -> same XCD.
    const int d     = blockIdx.y * gridDim.x + blockIdx.x;
    const int per   = (gridDim.x * gridDim.y) >> 3;   // total % 8 == 0
    const int w     = (d & 7) * per + (d >> 3);
    const int chunk = w % NBLK, n = w / NBLK;

    const int tid = threadIdx.x, lane = tid & 63, wid = tid >> 6;

    const float alpha = sigmoidf(za[n]);
    const float omah  = 0.5f * (1.0f - alpha);
    const float A16K  = powiu(alpha, IIRL);   // 0 unless alpha > 0.9947
    const float Tthr  = lt[n] - 6.0f;
    const float ratio = 1.0f + __expf(lr[n]);
    const float knee  = __expf(lk[n] - 1.0f);
    const float coef  = (1.0f / ratio - 1.0f) / knee;

    const float a4    = (alpha * alpha) * (alpha * alpha);
    const float a256  = powiu(a4, 64u);
    const float A1024 = powiu(a256, 4u);

    const long  base = (long)n * 2 * LLEN + (long)chunk * CHUNK;
    const float* x0 = x + base;
    const float* x1 = x0 + LLEN;
    const int woff = wid * 1024;          // wave segment offset in chunk

    // ---- own tile: coalesced loads, kept in registers ----
    float4 xa[4], xb[4];
    {
        const float4* p0 = reinterpret_cast<const float4*>(x0 + woff);
        const float4* p1 = reinterpret_cast<const float4*>(x1 + woff);
        #pragma unroll
        for (int q = 0; q < 4; ++q) {
            xa[q] = p0[q * 64 + lane];
            xb[q] = p1[q * 64 + lane];
        }
    }

    // b values for own tile (recurrence input)
    float b[4][4];
    #pragma unroll
    for (int q = 0; q < 4; ++q) {
        float4 a = xa[q], c = xb[q];
        b[q][0] = omah * fmaf(a.x, a.x, c.x * c.x);
        b[q][1] = omah * fmaf(a.y, a.y, c.y * c.y);
        b[q][2] = omah * fmaf(a.z, a.z, c.z * c.z);
        b[q][3] = omah * fmaf(a.w, a.w, c.w * c.w);
    }

    // ---- prev-chunk pass: per-group chains sq[q] + rare tail correction ----
    float sq[4] = {0.f, 0.f, 0.f, 0.f};
    if (chunk > 0) {
        const float4* r0 = reinterpret_cast<const float4*>(x0 - CHUNK + woff);
        const float4* r1 = reinterpret_cast<const float4*>(x1 - CHUNK + woff);
        const float sc = A16K * omah;
        #pragma unroll
        for (int q = 0; q < 4; ++q) {
            float4 a = r0[q * 64 + lane], c = r1[q * 64 + lane];
            float l0 = fmaf(a.x, a.x, c.x * c.x);
            float l1 = fmaf(a.y, a.y, c.y * c.y);
            float l2 = fmaf(a.z, a.z, c.z * c.z);
            float l3 = fmaf(a.w, a.w, c.w * c.w);
            float s = omah * l0;
            s = fmaf(alpha, s, omah * l1);
            s = fmaf(alpha, s, omah * l2);
            s = fmaf(alpha, s, omah * l3);
            sq[q] = s;
            if (A16K != 0.0f) {               // exact-tail path, ~never taken
                b[q][0] -= sc * l0; b[q][1] -= sc * l1;
                b[q][2] -= sc * l2; b[q][3] -= sc * l3;
            }
        }
    }

    // per-thread run totals rt_q (4 independent chains)
    float rt[4];
    #pragma unroll
    for (int q = 0; q < 4; ++q) {
        float s = b[q][0];
        s = fmaf(alpha, s, b[q][1]);
        s = fmaf(alpha, s, b[q][2]);
        s = fmaf(alpha, s, b[q][3]);
        rt[q] = s;
    }

    // ---- 4 interleaved wave scans over lanes (ratio a^4, own chunk) ----
    float v0 = rt[0], v1 = rt[1], v2 = rt[2], v3 = rt[3];
    float g = a4;
    #pragma unroll
    for (int off = 1; off < 64; off <<= 1) {
        float y0 = __shfl_up(v0, off, 64);
        float y1 = __shfl_up(v1, off, 64);
        float y2 = __shfl_up(v2, off, 64);
        float y3 = __shfl_up(v3, off, 64);
        if (lane >= off) {
            v0 = fmaf(g, y0, v0); v1 = fmaf(g, y1, v1);
            v2 = fmaf(g, y2, v2); v3 = fmaf(g, y3, v3);
        }
        g *= g;
    }
    float Ex[4];
    Ex[0] = __shfl_up(v0, 1, 64); Ex[1] = __shfl_up(v1, 1, 64);
    Ex[2] = __shfl_up(v2, 1, 64); Ex[3] = __shfl_up(v3, 1, 64);
    if (lane == 0) { Ex[0] = Ex[1] = Ex[2] = Ex[3] = 0.0f; }
    float S[4];
    S[0] = __shfl(v0, 63, 64); S[1] = __shfl(v1, 63, 64);
    S[2] = __shfl(v2, 63, 64); S[3] = __shfl(v3, 63, 64);

    // wave total (1024 elems): Horner over run blocks
    float W = S[0];
    W = fmaf(a256, W, S[1]); W = fmaf(a256, W, S[2]); W = fmaf(a256, W, S[3]);

    // prev-chunk wave total: butterfly per q-block, combine with a256 weights
    float uw = 0.0f;
    if (chunk > 0) {
        const float lw = powiu(a4, (unsigned)(63 - lane));
        float t0 = sq[0] * lw, t1 = sq[1] * lw, t2 = sq[2] * lw, t3 = sq[3] * lw;
        #pragma unroll
        for (int off = 32; off; off >>= 1) {
            t0 += __shfl_xor(t0, off, 64);
            t1 += __shfl_xor(t1, off, 64);
            t2 += __shfl_xor(t2, off, 64);
            t3 += __shfl_xor(t3, off, 64);
        }
        uw = t0;                               // uw = a256^3 t0 + ... + t3
        uw = fmaf(a256, uw, t1);
        uw = fmaf(a256, uw, t2);
        uw = fmaf(a256, uw, t3);
    }

    __shared__ float wtB[NW], wtP[NW];
    if (lane == 0) { wtB[wid] = W; wtP[wid] = uw; }
    __syncthreads();

    // block-level: carry T(c-1) + exclusive prefix over waves (own chunk)
    float C = 0.0f;
    #pragma unroll
    for (int ww = 0; ww < NW; ++ww) C = fmaf(A1024, C, wtP[ww]);
    float wc = 0.0f;
    for (int ww = 0; ww < wid; ++ww) wc = fmaf(A1024, wc, wtB[ww]);

    const float e_wave = fmaf(powiu(A1024, (unsigned)wid), C, wc);
    const float a4l    = powiu(a4, (unsigned)lane);

    // ---- apply gain + coalesced writes ----
    float cq = e_wave;                    // env before run-block q
    float4* o0 = reinterpret_cast<float4*>(out + base + woff);
    float4* o1 = reinterpret_cast<float4*>(out + base + LLEN + woff);
    #pragma unroll
    for (int q = 0; q < 4; ++q) {
        float e = fmaf(a4l, cq, Ex[q]);   // env before this thread's run
        cq = fmaf(a256, cq, S[q]);        // advance to next run block
        float4 a = xa[q], c = xb[q];
        float4 oa, ob;
        const float* ia = reinterpret_cast<const float*>(&a);
        const float* ib = reinterpret_cast<const float*>(&c);
        float* poa = reinterpret_cast<float*>(&oa);
        float* pob = reinterpret_cast<float*>(&ob);
        #pragma unroll
        for (int m = 0; m < 4; ++m) {
            e = fmaf(alpha, e, b[q][m]);
            float le = __logf(e + 1e-5f);
            float xk = knee * (le - Tthr);
            float sp = fmaxf(xk, 0.0f) + __logf(1.0f + __expf(-fabsf(xk)));
            float gain = __expf(coef * sp);
            poa[m] = gain * ia[m];
            pob[m] = gain * ib[m];
        }
        o0[q * 64 + lane] = oa;
        o1[q * 64 + lane] = ob;
    }
}

extern "C" void kernel_launch(void* const* d_in, const int* in_sizes, int n_in,
                              void* d_out, int out_size, void* d_ws, size_t ws_size,
                              hipStream_t stream) {
    const float* x  = (const float*)d_in[0];
    const float* za = (const float*)d_in[1];
    const float* lt = (const float*)d_in[2];
    const float* lr = (const float*)d_in[3];
    const float* lk = (const float*)d_in[4];
    float* out = (float*)d_out;

    const int N = in_sizes[1];             // z_alpha is (N,1)
    dim3 grid(NBLK, N), block(TPB);
    k_fused<<<grid, block, 0, stream>>>(x, za, lt, lr, lk, out);
}